// Round 1
// baseline (391.625 us; speedup 1.0000x reference)
//
#include <hip/hip_runtime.h>
#include <math.h>

#define N 8192
#define D 128
#define MARGIN_V 0.3f
#define NEG_FILL 1000000.0f

// ---------------- prep: sq[i] = ||f_i||^2, init ap/an ----------------
__global__ __launch_bounds__(256) void prep_kernel(const float* __restrict__ F,
                                                   float* __restrict__ sq,
                                                   unsigned* __restrict__ ap,
                                                   unsigned* __restrict__ an) {
    int row  = blockIdx.x * 4 + (threadIdx.x >> 6);   // 4 waves / block
    int lane = threadIdx.x & 63;
    float v0 = F[row * D + lane];
    float v1 = F[row * D + 64 + lane];
    float s  = v0 * v0 + v1 * v1;
    #pragma unroll
    for (int off = 32; off >= 1; off >>= 1) s += __shfl_xor(s, off);
    if (lane == 0) {
        sq[row] = s;
        ap[row] = 0u;            // max over positives, all dists >= 0
        an[row] = 0x7F800000u;   // +inf
    }
}

// ---------------- tile: 64x64 distance tile + hard mining ----------------
// lane map: tx = tid&15, ty = tid>>4; rows i = a*16+ty, cols j = b*16+tx
#define LDA 68   // 68 floats = 272 B = 17*16 B (16B aligned rows), 68%32=4
__global__ __launch_bounds__(256) void tile_kernel(const float* __restrict__ F,
                                                   const float* __restrict__ sq,
                                                   const int* __restrict__ lab,
                                                   unsigned* __restrict__ ap,
                                                   unsigned* __restrict__ an) {
    __shared__ float As[64 * LDA];
    __shared__ float Bs[64 * LDA];

    const int NT = N / 64;               // 128 tiles per dim
    int bi = blockIdx.x / NT;
    int bj = blockIdx.x % NT;
    int i0 = bi * 64, j0 = bj * 64;
    int tid = threadIdx.x;
    int tx = tid & 15, ty = tid >> 4;

    float acc[4][4];
    #pragma unroll
    for (int a = 0; a < 4; ++a)
        #pragma unroll
        for (int b = 0; b < 4; ++b) acc[a][b] = 0.0f;

    for (int kb = 0; kb < 2; ++kb) {     // two 64-wide K stages
        // stage 64 rows x 64 cols of A and B into LDS (float4, coalesced)
        #pragma unroll
        for (int it = 0; it < 4; ++it) {
            int f4 = it * 256 + tid;         // 0..1023
            int r  = f4 >> 4;                // /16 rows
            int c  = (f4 & 15) << 2;         // *4 cols
            float4 va = *(const float4*)&F[(i0 + r) * D + kb * 64 + c];
            float4 vb = *(const float4*)&F[(j0 + r) * D + kb * 64 + c];
            *(float4*)&As[r * LDA + c] = va;
            *(float4*)&Bs[r * LDA + c] = vb;
        }
        __syncthreads();

        #pragma unroll
        for (int k = 0; k < 64; k += 4) {
            float4 av[4], bv[4];
            #pragma unroll
            for (int a = 0; a < 4; ++a) av[a] = *(const float4*)&As[(a * 16 + ty) * LDA + k];
            #pragma unroll
            for (int b = 0; b < 4; ++b) bv[b] = *(const float4*)&Bs[(b * 16 + tx) * LDA + k];
            #pragma unroll
            for (int a = 0; a < 4; ++a)
                #pragma unroll
                for (int b = 0; b < 4; ++b) {
                    acc[a][b] += av[a].x * bv[b].x;
                    acc[a][b] += av[a].y * bv[b].y;
                    acc[a][b] += av[a].z * bv[b].z;
                    acc[a][b] += av[a].w * bv[b].w;
                }
        }
        __syncthreads();
    }

    // epilogue: distances, masks, per-row hard mining
    #pragma unroll
    for (int a = 0; a < 4; ++a) {
        int ig    = i0 + a * 16 + ty;
        float sqi = sq[ig];
        int   li  = lab[ig];
        float pmax = 0.0f;       // empty-positive -> 0 (matches ref)
        float nmin = INFINITY;
        #pragma unroll
        for (int b = 0; b < 4; ++b) {
            int jg   = j0 + b * 16 + tx;
            float d2 = sqi + sq[jg] - 2.0f * acc[a][b];
            d2 = fmaxf(d2, 0.0f);
            float dist = sqrtf(d2);
            int lj = lab[jg];
            bool same = (li == lj);
            if (same && (ig != jg)) pmax = fmaxf(pmax, dist);
            if (!same)              nmin = fminf(nmin, dist);
        }
        // reduce across the 16 tx lanes (stay within 16-lane groups)
        #pragma unroll
        for (int off = 1; off < 16; off <<= 1) {
            pmax = fmaxf(pmax, __shfl_xor(pmax, off));
            nmin = fminf(nmin, __shfl_xor(nmin, off));
        }
        if (tx == 0) {
            if (pmax > 0.0f)    atomicMax(&ap[ig], __float_as_uint(pmax));
            if (nmin < INFINITY) atomicMin(&an[ig], __float_as_uint(nmin));
        }
    }
}

// ---------------- loss: mean hinge ----------------
__global__ __launch_bounds__(256) void loss_kernel(const unsigned* __restrict__ ap,
                                                   const unsigned* __restrict__ an,
                                                   float* __restrict__ out) {
    __shared__ float sdata[4];
    int tid = threadIdx.x;
    float sum = 0.0f;
    for (int i = tid; i < N; i += 256) {
        float a  = __uint_as_float(ap[i]);
        float nv = __uint_as_float(an[i]);
        if (!(nv < INFINITY)) nv = NEG_FILL;   // empty-negative -> 1e6
        float l = MARGIN_V - (nv - a);
        sum += fmaxf(l, 0.0f);
    }
    #pragma unroll
    for (int off = 32; off >= 1; off >>= 1) sum += __shfl_xor(sum, off);
    if ((tid & 63) == 0) sdata[tid >> 6] = sum;
    __syncthreads();
    if (tid == 0) {
        float t = sdata[0] + sdata[1] + sdata[2] + sdata[3];
        out[0] = t / (float)N;
    }
}

extern "C" void kernel_launch(void* const* d_in, const int* in_sizes, int n_in,
                              void* d_out, int out_size, void* d_ws, size_t ws_size,
                              hipStream_t stream) {
    const float* F   = (const float*)d_in[0];
    const int*   lab = (const int*)d_in[1];

    float*    sq = (float*)d_ws;
    unsigned* ap = (unsigned*)(sq + N);
    unsigned* an = ap + N;

    prep_kernel<<<N / 4, 256, 0, stream>>>(F, sq, ap, an);
    tile_kernel<<<(N / 64) * (N / 64), 256, 0, stream>>>(F, sq, lab, ap, an);
    loss_kernel<<<1, 256, 0, stream>>>(ap, an, (float*)d_out);
}

// Round 2
// 137.321 us; speedup vs baseline: 2.8519x; 2.8519x over previous
//
#include <hip/hip_runtime.h>
#include <hip/hip_bf16.h>
#include <math.h>

#define N 8192
#define D 128
#define MARGIN_V 0.3f
#define NEG_FILL 1000000.0f

typedef short bf16x8 __attribute__((ext_vector_type(8)));
typedef float f32x4  __attribute__((ext_vector_type(4)));

__device__ __forceinline__ void g2l16(const void* g, void* l) {
    __builtin_amdgcn_global_load_lds(
        (const __attribute__((address_space(1))) void*)g,
        (__attribute__((address_space(3))) void*)l, 16, 0, 0);
}

// ---------- convert: F fp32 -> bf16, sq[i] = ||f_i||^2 (fp32-exact) ----------
__global__ __launch_bounds__(256) void convert_kernel(const float* __restrict__ F,
                                                      unsigned short* __restrict__ Fb,
                                                      float* __restrict__ sq) {
    int row  = blockIdx.x * 4 + (threadIdx.x >> 6);   // one wave per row
    int lane = threadIdx.x & 63;
    float2 v = *(const float2*)&F[row * D + lane * 2];
    float s = v.x * v.x + v.y * v.y;
    __hip_bfloat162 t = __float22bfloat162_rn(v);
    *(unsigned int*)&Fb[row * D + lane * 2] = *(unsigned int*)&t;
    #pragma unroll
    for (int off = 32; off >= 1; off >>= 1) s += __shfl_xor(s, off);
    if (lane == 0) sq[row] = s;
}

// ---------- init (atomic fallback path only) ----------
__global__ __launch_bounds__(256) void init_kernel(unsigned* __restrict__ ap,
                                                   unsigned* __restrict__ an) {
    int i = blockIdx.x * 256 + threadIdx.x;
    ap[i] = 0u;            // max identity (dist >= 0)
    an[i] = 0x7F800000u;   // +inf
}

// ---------- gemm: 128x128 C-tile, bf16 MFMA, fused mining epilogue ----------
// wave layout: 4 waves in 2x2; each wave 64x64 via 4x4 frags of 16x16x32
// A-frag: A[m=lane&15][k=quad*8+j]; C/D: col=lane&15, row=quad*4+reg
template <bool PARTIAL>
__global__ __launch_bounds__(256) void gemm_kernel(const unsigned short* __restrict__ Fb,
                                                   const float* __restrict__ sq,
                                                   const int* __restrict__ lab,
                                                   float* __restrict__ pap,
                                                   float* __restrict__ pan) {
    __shared__ unsigned short As[128 * 64];   // 16 KB, row-major [row][k]
    __shared__ unsigned short Bs[128 * 64];   // 16 KB
    __shared__ float sqi_s[128], sqj_s[128];
    __shared__ int   labi_s[128], labj_s[128];
    __shared__ float red_ap[2][128], red_an[2][128];

    const int bj = blockIdx.x, bi = blockIdx.y;
    const int i0 = bi * 128, j0 = bj * 128;
    const int tid  = threadIdx.x;
    const int wave = tid >> 6, lane = tid & 63;
    const int wy = wave >> 1, wx = wave & 1;
    const int quad = lane >> 4, lr = lane & 15;

    if (tid < 128) {
        sqi_s[tid] = sq[i0 + tid];
        labi_s[tid] = lab[i0 + tid];
    } else {
        int t = tid - 128;
        sqj_s[t] = sq[j0 + t];
        labj_s[t] = lab[j0 + t];
    }

    f32x4 acc[4][4];
    #pragma unroll
    for (int a = 0; a < 4; ++a)
        #pragma unroll
        for (int b = 0; b < 4; ++b) acc[a][b] = {0.f, 0.f, 0.f, 0.f};

    for (int kb = 0; kb < 2; ++kb) {
        // stage A/B tiles: 128 rows x 64 k of bf16 each, async direct-to-LDS
        #pragma unroll
        for (int it = 0; it < 4; ++it) {
            int row = it * 32 + (tid >> 3);
            int kc  = (tid & 7) * 8;
            g2l16(Fb + (i0 + row) * D + kb * 64 + kc, (char*)As + it * 4096 + tid * 16);
            g2l16(Fb + (j0 + row) * D + kb * 64 + kc, (char*)Bs + it * 4096 + tid * 16);
        }
        __syncthreads();

        #pragma unroll
        for (int ks = 0; ks < 64; ks += 32) {
            bf16x8 af[4], bfr[4];
            #pragma unroll
            for (int a = 0; a < 4; ++a)
                af[a] = *(const bf16x8*)&As[(wy * 64 + a * 16 + lr) * 64 + ks + quad * 8];
            #pragma unroll
            for (int b = 0; b < 4; ++b)
                bfr[b] = *(const bf16x8*)&Bs[(wx * 64 + b * 16 + lr) * 64 + ks + quad * 8];
            #pragma unroll
            for (int a = 0; a < 4; ++a)
                #pragma unroll
                for (int b = 0; b < 4; ++b)
                    acc[a][b] = __builtin_amdgcn_mfma_f32_16x16x32_bf16(af[a], bfr[b], acc[a][b], 0, 0, 0);
        }
        __syncthreads();
    }

    // epilogue: distance + masked hard mining, reduce along j
    #pragma unroll
    for (int a = 0; a < 4; ++a) {
        #pragma unroll
        for (int r = 0; r < 4; ++r) {
            int rl  = wy * 64 + a * 16 + quad * 4 + r;
            float sqi = sqi_s[rl];
            int   li  = labi_s[rl];
            int   ig  = i0 + rl;
            float pmax = 0.f, nmin = INFINITY;
            #pragma unroll
            for (int b = 0; b < 4; ++b) {
                int cl = wx * 64 + b * 16 + lr;
                float c  = acc[a][b][r];
                float d2 = sqi + sqj_s[cl] - 2.0f * c;
                float dist = sqrtf(fmaxf(d2, 0.f));
                bool same = (li == labj_s[cl]);
                bool diag = (ig == j0 + cl);
                if (same && !diag) pmax = fmaxf(pmax, dist);
                if (!same)         nmin = fminf(nmin, dist);
            }
            #pragma unroll
            for (int off = 1; off < 16; off <<= 1) {
                pmax = fmaxf(pmax, __shfl_xor(pmax, off));
                nmin = fminf(nmin, __shfl_xor(nmin, off));
            }
            if (lr == 0) { red_ap[wx][rl] = pmax; red_an[wx][rl] = nmin; }
        }
    }
    __syncthreads();

    if (tid < 128) {
        float pmax = fmaxf(red_ap[0][tid], red_ap[1][tid]);
        float nmin = fminf(red_an[0][tid], red_an[1][tid]);
        if (PARTIAL) {
            pap[(size_t)bj * N + i0 + tid] = pmax;
            pan[(size_t)bj * N + i0 + tid] = nmin;
        } else {
            atomicMax((unsigned*)pap + i0 + tid, __float_as_uint(pmax));
            atomicMin((unsigned*)pan + i0 + tid, __float_as_uint(nmin));
        }
    }
}

// ---------- loss: combine partials, hinge, mean ----------
template <bool PARTIAL>
__global__ __launch_bounds__(256) void loss_kernel(const float* __restrict__ pap,
                                                   const float* __restrict__ pan,
                                                   float* __restrict__ out) {
    int i = blockIdx.x * 256 + threadIdx.x;
    float ap, an;
    if (PARTIAL) {
        ap = 0.f; an = INFINITY;
        for (int b = 0; b < 64; ++b) {
            ap = fmaxf(ap, pap[(size_t)b * N + i]);
            an = fminf(an, pan[(size_t)b * N + i]);
        }
    } else {
        ap = __uint_as_float(((const unsigned*)pap)[i]);
        an = __uint_as_float(((const unsigned*)pan)[i]);
    }
    if (!(an < INFINITY)) an = NEG_FILL;
    float l = fmaxf(0.f, MARGIN_V - (an - ap));
    #pragma unroll
    for (int off = 32; off >= 1; off >>= 1) l += __shfl_xor(l, off);
    __shared__ float s4[4];
    if ((threadIdx.x & 63) == 0) s4[threadIdx.x >> 6] = l;
    __syncthreads();
    if (threadIdx.x == 0)
        atomicAdd(out, (s4[0] + s4[1] + s4[2] + s4[3]) * (1.0f / (float)N));
}

extern "C" void kernel_launch(void* const* d_in, const int* in_sizes, int n_in,
                              void* d_out, int out_size, void* d_ws, size_t ws_size,
                              hipStream_t stream) {
    const float* F   = (const float*)d_in[0];
    const int*   lab = (const int*)d_in[1];

    unsigned short* Fb = (unsigned short*)d_ws;          // 2 MB
    float*          sq = (float*)(Fb + (size_t)N * D);   // 32 KB
    char*           p  = (char*)(sq + N);
    size_t used = (size_t)(p - (char*)d_ws);
    bool partial = (ws_size >= used + (size_t)2 * 64 * N * sizeof(float) + 256);

    hipMemsetAsync(d_out, 0, sizeof(float), stream);
    convert_kernel<<<N / 4, 256, 0, stream>>>(F, Fb, sq);

    dim3 grid(64, 64);
    if (partial) {
        float* pap = (float*)p;
        float* pan = pap + (size_t)64 * N;
        gemm_kernel<true><<<grid, 256, 0, stream>>>(Fb, sq, lab, pap, pan);
        loss_kernel<true><<<N / 256, 256, 0, stream>>>(pap, pan, (float*)d_out);
    } else {
        unsigned* ap = (unsigned*)p;
        unsigned* an = ap + N;
        init_kernel<<<N / 256, 256, 0, stream>>>(ap, an);
        gemm_kernel<false><<<grid, 256, 0, stream>>>(Fb, sq, lab, (float*)ap, (float*)an);
        loss_kernel<false><<<N / 256, 256, 0, stream>>>((const float*)ap, (const float*)an, (float*)d_out);
    }
}

// Round 4
// 105.948 us; speedup vs baseline: 3.6964x; 1.2961x over previous
//
#include <hip/hip_runtime.h>
#include <hip/hip_bf16.h>
#include <math.h>

#define N 8192
#define D 128
#define NB 64            // 8192/128 block-rows
#define MARGIN_V 0.3f
#define NEG_FILL 1000000.0f

typedef short bf16x8 __attribute__((ext_vector_type(8)));
typedef float f32x4  __attribute__((ext_vector_type(4)));

__device__ __forceinline__ void g2l16(const void* g, void* l) {
    __builtin_amdgcn_global_load_lds(
        (const __attribute__((address_space(1))) void*)g,
        (__attribute__((address_space(3))) void*)l, 16, 0, 0);
}

// ---------- convert: F fp32 -> bf16, sq[i] = ||f_i||^2 (fp32-exact) ----------
__global__ __launch_bounds__(256) void convert_kernel(const float* __restrict__ F,
                                                      unsigned short* __restrict__ Fb,
                                                      float* __restrict__ sq) {
    int row  = blockIdx.x * 4 + (threadIdx.x >> 6);
    int lane = threadIdx.x & 63;
    float2 v = *(const float2*)&F[row * D + lane * 2];
    float s = v.x * v.x + v.y * v.y;
    __hip_bfloat162 t = __float22bfloat162_rn(v);
    *(unsigned int*)&Fb[row * D + lane * 2] = *(unsigned int*)&t;
    #pragma unroll
    for (int off = 32; off >= 1; off >>= 1) s += __shfl_xor(s, off);
    if (lane == 0) sq[row] = s;
}

// ---------- init (atomic fallback path only) ----------
__global__ __launch_bounds__(256) void init_kernel(unsigned* __restrict__ ap,
                                                   unsigned* __restrict__ an) {
    int i = blockIdx.x * 256 + threadIdx.x;
    ap[i] = 0u;
    an[i] = 0x7F800000u;
}

// ---------- gemm: upper-triangle 128x128 tiles, swizzled LDS, dual mining ----------
// wave layout 2x2; wave computes 64x64 via 4x4 frags of 16x16x32 bf16.
// A-frag: A[m=lane&15][k=quad*8+j]; C/D: col=lane&15, row=quad*4+reg.
// LDS tile layout: 16B chunk for (row, kchunk) stored at chunk pos (kchunk ^ (row&7)).
template <bool PARTIAL>
__global__ __launch_bounds__(256) void gemm_kernel(const unsigned short* __restrict__ Fb,
                                                   const float* __restrict__ sq,
                                                   const int* __restrict__ lab,
                                                   float* __restrict__ pap,
                                                   float* __restrict__ pan) {
    __shared__ __align__(16) char pool[34816];   // staging 32 KB | reduce 33.8 KB
    __shared__ float sqi_s[128], sqj_s[128];
    __shared__ int   labi_s[128], labj_s[128];

    unsigned short* As = (unsigned short*)pool;            // 16 KB
    unsigned short* Bs = (unsigned short*)(pool + 16384);  // 16 KB

    // ---- triangular block decode: t -> (bi, bj), bi <= bj ----
    int t = blockIdx.x;
    int bi = (int)((2 * NB + 1 - sqrtf((float)((2 * NB + 1) * (2 * NB + 1) - 8 * t))) * 0.5f);
    if (bi < 0) bi = 0;
    if (bi > NB - 1) bi = NB - 1;
    int start = bi * NB - (bi * (bi - 1)) / 2;
    while (t < start)                { --bi; start = bi * NB - (bi * (bi - 1)) / 2; }
    while (t >= start + (NB - bi))   { ++bi; start = bi * NB - (bi * (bi - 1)) / 2; }
    int bj = bi + (t - start);
    const bool diagBlk = (bi == bj);

    const int i0 = bi * 128, j0 = bj * 128;
    const int tid  = threadIdx.x;
    const int wave = tid >> 6, lane = tid & 63;
    const int wy = wave >> 1, wx = wave & 1;
    const int quad = lane >> 4, lr = lane & 15;
    const int swz = lr & 7;

    if (tid < 128) {
        sqi_s[tid]  = sq[i0 + tid];
        labi_s[tid] = lab[i0 + tid];
    } else {
        int u = tid - 128;
        sqj_s[u]  = sq[j0 + u];
        labj_s[u] = lab[j0 + u];
    }

    f32x4 acc[4][4];
    #pragma unroll
    for (int a = 0; a < 4; ++a)
        #pragma unroll
        for (int b = 0; b < 4; ++b) acc[a][b] = {0.f, 0.f, 0.f, 0.f};

    const int srow = tid >> 3;          // staging row within 32-row group
    const int cpos = tid & 7;           // staged chunk position within row
    const int skc  = (cpos ^ (srow & 7)) * 8;   // swizzled source k offset (shorts)

    for (int kb = 0; kb < 2; ++kb) {
        #pragma unroll
        for (int it = 0; it < 4; ++it) {
            int row = it * 32 + srow;
            g2l16(Fb + (size_t)(i0 + row) * D + kb * 64 + skc, (char*)As + it * 4096 + tid * 16);
            g2l16(Fb + (size_t)(j0 + row) * D + kb * 64 + skc, (char*)Bs + it * 4096 + tid * 16);
        }
        __syncthreads();

        #pragma unroll
        for (int ks8 = 0; ks8 < 8; ks8 += 4) {       // k chunk base: 0, 4
            bf16x8 af[4], bfr[4];
            #pragma unroll
            for (int a = 0; a < 4; ++a)
                af[a] = *(const bf16x8*)&As[(wy * 64 + a * 16 + lr) * 64 + (((ks8 + quad) ^ swz) * 8)];
            #pragma unroll
            for (int b = 0; b < 4; ++b)
                bfr[b] = *(const bf16x8*)&Bs[(wx * 64 + b * 16 + lr) * 64 + (((ks8 + quad) ^ swz) * 8)];
            #pragma unroll
            for (int a = 0; a < 4; ++a)
                #pragma unroll
                for (int b = 0; b < 4; ++b)
                    acc[a][b] = __builtin_amdgcn_mfma_f32_16x16x32_bf16(af[a], bfr[b], acc[a][b], 0, 0, 0);
        }
        __syncthreads();
    }

    // ---- phase A: per-thread distances + row/col partial mining ----
    float rowP[4][4], rowN[4][4];   // [a][r]: rows wy*64+a*16+quad*4+r
    float colP[4],    colN[4];      // [b]:    cols wx*64+b*16+lr
    float sqj_r[4]; int labj_r[4], cl_r[4];
    #pragma unroll
    for (int b = 0; b < 4; ++b) {
        int cl = wx * 64 + b * 16 + lr;
        cl_r[b] = cl; sqj_r[b] = sqj_s[cl]; labj_r[b] = labj_s[cl];
        colP[b] = 0.f; colN[b] = INFINITY;
    }
    #pragma unroll
    for (int a = 0; a < 4; ++a) {
        #pragma unroll
        for (int r = 0; r < 4; ++r) {
            int rl = wy * 64 + a * 16 + quad * 4 + r;
            float sqi = sqi_s[rl];
            int   li  = labi_s[rl];
            float pmax = 0.f, nmin = INFINITY;
            #pragma unroll
            for (int b = 0; b < 4; ++b) {
                float c  = acc[a][b][r];
                float d2 = fmaxf(sqi + sqj_r[b] - 2.0f * c, 0.f);
                float dist = __builtin_amdgcn_sqrtf(d2);
                bool same = (li == labj_r[b]);
                bool dia  = diagBlk && (rl == cl_r[b]);
                float pv = (same && !dia) ? dist : 0.f;
                float nv = same ? INFINITY : dist;
                pmax = fmaxf(pmax, pv);  nmin = fminf(nmin, nv);
                colP[b] = fmaxf(colP[b], pv);  colN[b] = fminf(colN[b], nv);
            }
            rowP[a][r] = pmax; rowN[a][r] = nmin;
        }
    }
    __syncthreads();   // all frag reads of As/Bs done -> reuse pool

    // ---- phase B1: row mining reduce via LDS transpose ----
    float (*rp)[132] = (float(*)[132])pool;             // [32 col-lanes][132 rows(pad)]
    float (*rn)[132] = (float(*)[132])(pool + 16896);
    {
        int c = wx * 16 + lr;
        #pragma unroll
        for (int a = 0; a < 4; ++a) {
            int base = wy * 64 + a * 16 + quad * 4;
            *(f32x4*)&rp[c][base] = *(f32x4*)&rowP[a][0];
            *(f32x4*)&rn[c][base] = *(f32x4*)&rowN[a][0];
        }
    }
    __syncthreads();
    if (tid < 128) {
        int row = tid;
        float m = rp[0][row];
        #pragma unroll
        for (int c = 1; c < 32; ++c) m = fmaxf(m, rp[c][row]);
        if (PARTIAL) pap[(size_t)bj * N + i0 + row] = m;
        else if (m > 0.f) atomicMax((unsigned*)pap + i0 + row, __float_as_uint(m));
    } else {
        int row = tid - 128;
        float m = rn[0][row];
        #pragma unroll
        for (int c = 1; c < 32; ++c) m = fminf(m, rn[c][row]);
        if (PARTIAL) pan[(size_t)bj * N + i0 + row] = m;
        else if (m < INFINITY) atomicMin((unsigned*)pan + i0 + row, __float_as_uint(m));
    }

    // ---- phase B2: column mining (off-diagonal blocks only) ----
    if (!diagBlk) {
        __syncthreads();   // row reduce reads done -> reuse pool again
        float (*cp)[9] = (float(*)[9])pool;             // [128 cols][9(pad)]
        float (*cn)[9] = (float(*)[9])(pool + 4608);
        int ct = wy * 4 + quad;
        #pragma unroll
        for (int b = 0; b < 4; ++b) {
            cp[cl_r[b]][ct] = colP[b];
            cn[cl_r[b]][ct] = colN[b];
        }
        __syncthreads();
        if (tid < 128) {
            int col = tid;
            float m = cp[col][0];
            #pragma unroll
            for (int c = 1; c < 8; ++c) m = fmaxf(m, cp[col][c]);
            if (PARTIAL) pap[(size_t)bi * N + j0 + col] = m;
            else if (m > 0.f) atomicMax((unsigned*)pap + j0 + col, __float_as_uint(m));
        } else {
            int col = tid - 128;
            float m = cn[col][0];
            #pragma unroll
            for (int c = 1; c < 8; ++c) m = fminf(m, cn[col][c]);
            if (PARTIAL) pan[(size_t)bi * N + j0 + col] = m;
            else if (m < INFINITY) atomicMin((unsigned*)pan + j0 + col, __float_as_uint(m));
        }
    }
}

// ---------- loss: combine partials, hinge, mean ----------
template <bool PARTIAL>
__global__ __launch_bounds__(256) void loss_kernel(const float* __restrict__ pap,
                                                   const float* __restrict__ pan,
                                                   float* __restrict__ out) {
    int i = blockIdx.x * 256 + threadIdx.x;
    float ap, an;
    if (PARTIAL) {
        ap = 0.f; an = INFINITY;
        for (int b = 0; b < NB; ++b) {
            ap = fmaxf(ap, pap[(size_t)b * N + i]);
            an = fminf(an, pan[(size_t)b * N + i]);
        }
    } else {
        ap = __uint_as_float(((const unsigned*)pap)[i]);
        an = __uint_as_float(((const unsigned*)pan)[i]);
    }
    if (!(an < INFINITY)) an = NEG_FILL;
    float l = fmaxf(0.f, MARGIN_V - (an - ap));
    #pragma unroll
    for (int off = 32; off >= 1; off >>= 1) l += __shfl_xor(l, off);
    __shared__ float s4[4];
    if ((threadIdx.x & 63) == 0) s4[threadIdx.x >> 6] = l;
    __syncthreads();
    if (threadIdx.x == 0)
        atomicAdd(out, (s4[0] + s4[1] + s4[2] + s4[3]) * (1.0f / (float)N));
}

extern "C" void kernel_launch(void* const* d_in, const int* in_sizes, int n_in,
                              void* d_out, int out_size, void* d_ws, size_t ws_size,
                              hipStream_t stream) {
    const float* F   = (const float*)d_in[0];
    const int*   lab = (const int*)d_in[1];

    unsigned short* Fb = (unsigned short*)d_ws;          // 2 MB
    float*          sq = (float*)(Fb + (size_t)N * D);   // 32 KB
    char*           p  = (char*)(sq + N);
    size_t used = (size_t)(p - (char*)d_ws);
    bool partial = (ws_size >= used + (size_t)2 * NB * N * sizeof(float) + 256);

    hipMemsetAsync(d_out, 0, sizeof(float), stream);
    convert_kernel<<<N / 4, 256, 0, stream>>>(F, Fb, sq);

    const int ntri = NB * (NB + 1) / 2;   // 2080
    if (partial) {
        float* pap = (float*)p;
        float* pan = pap + (size_t)NB * N;
        gemm_kernel<true><<<ntri, 256, 0, stream>>>(Fb, sq, lab, pap, pan);
        loss_kernel<true><<<N / 256, 256, 0, stream>>>(pap, pan, (float*)d_out);
    } else {
        unsigned* ap = (unsigned*)p;
        unsigned* an = ap + N;
        init_kernel<<<N / 256, 256, 0, stream>>>(ap, an);
        gemm_kernel<false><<<ntri, 256, 0, stream>>>(Fb, sq, lab, (float*)ap, (float*)an);
        loss_kernel<false><<<N / 256, 256, 0, stream>>>((const float*)ap, (const float*)an, (float*)d_out);
    }
}

// Round 5
// 86.607 us; speedup vs baseline: 4.5219x; 1.2233x over previous
//
#include <hip/hip_runtime.h>
#include <hip/hip_bf16.h>
#include <math.h>

#define N 8192
#define D 128
#define MARGIN_V 0.3f
#define NEG_FILL 1000000.0f

typedef short bf16x8 __attribute__((ext_vector_type(8)));
typedef float f32x4  __attribute__((ext_vector_type(4)));

__device__ __forceinline__ void g2l16(const void* g, void* l) {
    __builtin_amdgcn_global_load_lds(
        (const __attribute__((address_space(1))) void*)g,
        (__attribute__((address_space(3))) void*)l, 16, 0, 0);
}

// ---------- convert: F fp32 -> bf16, sq[i] = ||f_i||^2; init ap/an ----------
__global__ __launch_bounds__(256) void convert_kernel(const float* __restrict__ F,
                                                      unsigned short* __restrict__ Fb,
                                                      float* __restrict__ sq,
                                                      unsigned* __restrict__ ap,
                                                      unsigned* __restrict__ an) {
    int row  = blockIdx.x * 4 + (threadIdx.x >> 6);
    int lane = threadIdx.x & 63;
    float2 v = *(const float2*)&F[row * D + lane * 2];
    float s = v.x * v.x + v.y * v.y;
    __hip_bfloat162 t = __float22bfloat162_rn(v);
    *(unsigned int*)&Fb[row * D + lane * 2] = *(unsigned int*)&t;
    #pragma unroll
    for (int off = 32; off >= 1; off >>= 1) s += __shfl_xor(s, off);
    if (lane == 0) sq[row] = s;
    int gid = blockIdx.x * 256 + threadIdx.x;
    if (gid < N) { ap[gid] = 0u; an[gid] = 0x7F800000u; }   // 0.0f / +inf (d^2 domain)
}

// ---------- gemm: 128-row strip x 1024-col chunk per block ----------
// grid 512 = 64 strips x 8 chunks = 2 blocks/CU. A resident in LDS+regs,
// B double-buffered (16 tiles of 64 cols). Mining in u = sqj - 2c domain,
// accumulated in registers; sqrt/clamp deferred. Atomic d^2-bits combine.
// LDS chunk swizzle: 16B chunk kc of row r stored at pos (kc&8)|((kc^r)&7).
__global__ __launch_bounds__(256, 2) void gemm_kernel(const unsigned short* __restrict__ Fb,
                                                      const float* __restrict__ sq,
                                                      const int* __restrict__ lab,
                                                      unsigned* __restrict__ ap,
                                                      unsigned* __restrict__ an) {
    __shared__ __align__(16) unsigned short As[128 * 128];    // 32 KB
    __shared__ __align__(16) unsigned short Bs[2][64 * 128];  // 2 x 16 KB
    __shared__ float sqj_s[1024];
    __shared__ int   labj_s[1024];
    __shared__ float sqi_s[128];
    __shared__ int   labi_s[128];

    const int bi = blockIdx.x & 63;
    const int jc = blockIdx.x >> 6;
    const int i0 = bi * 128;
    const int jbase0 = jc * 1024;
    const int tid  = threadIdx.x;
    const int wave = tid >> 6, lane = tid & 63;
    const int quad = lane >> 4, lr = lane & 15;

    // stage sq/lab for this block's rows and cols
    {
        f32x4 v = *(const f32x4*)&sq[jbase0 + tid * 4];
        *(f32x4*)&sqj_s[tid * 4] = v;
        int4 w4 = *(const int4*)&lab[jbase0 + tid * 4];
        *(int4*)&labj_s[tid * 4] = w4;
    }
    if (tid < 128) { sqi_s[tid] = sq[i0 + tid]; labi_s[tid] = lab[i0 + tid]; }

    // stage A tile (128 rows x 128 k), swizzled
    #pragma unroll
    for (int it = 0; it < 8; ++it) {
        int c_id = it * 256 + tid;
        int row = c_id >> 4, p = c_id & 15;
        int sc = (p & 8) | ((p ^ row) & 7);
        g2l16(Fb + (size_t)(i0 + row) * D + sc * 8, (char*)As + c_id * 16);
    }
    // stage B tile 0
    #pragma unroll
    for (int it = 0; it < 4; ++it) {
        int c_id = it * 256 + tid;
        int row = c_id >> 4, p = c_id & 15;
        int sc = (p & 8) | ((p ^ row) & 7);
        g2l16(Fb + (size_t)(jbase0 + row) * D + sc * 8, (char*)&Bs[0][0] + c_id * 16);
    }
    __syncthreads();

    // cache A fragments in registers for the whole block
    bf16x8 af[2][4];
    #pragma unroll
    for (int a = 0; a < 2; ++a)
        #pragma unroll
        for (int ks = 0; ks < 4; ++ks) {
            int row = wave * 32 + a * 16 + lr;
            int kc  = ks * 4 + quad;
            int pos = (kc & 8) | ((kc ^ row) & 7);
            af[a][ks] = *(const bf16x8*)&As[row * 128 + pos * 8];
        }
    f32x4 sqi4[2]; int4 labi4[2];
    #pragma unroll
    for (int a = 0; a < 2; ++a) {
        int base = wave * 32 + a * 16 + quad * 4;
        sqi4[a]  = *(const f32x4*)&sqi_s[base];
        labi4[a] = *(const int4*)&labi_s[base];
    }

    float rowP[2][4], rowN[2][4];
    #pragma unroll
    for (int a = 0; a < 2; ++a)
        #pragma unroll
        for (int r = 0; r < 4; ++r) { rowP[a][r] = -INFINITY; rowN[a][r] = INFINITY; }

    #pragma unroll 2
    for (int t = 0; t < 16; ++t) {
        // prefetch next B tile into the other buffer
        if (t < 15) {
            #pragma unroll
            for (int it = 0; it < 4; ++it) {
                int c_id = it * 256 + tid;
                int row = c_id >> 4, p = c_id & 15;
                int sc = (p & 8) | ((p ^ row) & 7);
                g2l16(Fb + (size_t)(jbase0 + (t + 1) * 64 + row) * D + sc * 8,
                      (char*)&Bs[(t + 1) & 1][0] + c_id * 16);
            }
        }
        // per-tile column metadata
        float sqj_l[4]; int labj_l[4];
        #pragma unroll
        for (int b = 0; b < 4; ++b) {
            sqj_l[b]  = sqj_s[t * 64 + b * 16 + lr];
            labj_l[b] = labj_s[t * 64 + b * 16 + lr];
        }
        // MFMA on current buffer
        f32x4 acc[2][4];
        #pragma unroll
        for (int a = 0; a < 2; ++a)
            #pragma unroll
            for (int b = 0; b < 4; ++b) acc[a][b] = {0.f, 0.f, 0.f, 0.f};
        #pragma unroll
        for (int ks = 0; ks < 4; ++ks) {
            bf16x8 bfr[4];
            #pragma unroll
            for (int b = 0; b < 4; ++b) {
                int rb  = b * 16 + lr;
                int kc  = ks * 4 + quad;
                int pos = (kc & 8) | ((kc ^ rb) & 7);
                bfr[b] = *(const bf16x8*)&Bs[t & 1][rb * 128 + pos * 8];
            }
            #pragma unroll
            for (int a = 0; a < 2; ++a)
                #pragma unroll
                for (int b = 0; b < 4; ++b)
                    acc[a][b] = __builtin_amdgcn_mfma_f32_16x16x32_bf16(af[a][ks], bfr[b], acc[a][b], 0, 0, 0);
        }
        __syncthreads();   // Bs reads done; prefetch drained; safe to overwrite next iter

        // epilogue: u = sqj - 2c mining (6 ops/elem), register-resident
        #pragma unroll
        for (int a = 0; a < 2; ++a)
            #pragma unroll
            for (int b = 0; b < 4; ++b)
                #pragma unroll
                for (int r = 0; r < 4; ++r) {
                    float u = fmaf(acc[a][b][r], -2.0f, sqj_l[b]);
                    bool same = (labi4[a][r] == labj_l[b]);
                    rowP[a][r] = fmaxf(rowP[a][r], same ? u : -INFINITY);
                    rowN[a][r] = fminf(rowN[a][r], same ? INFINITY : u);
                }
    }

    // reduce over the 16 lr lanes, then atomically combine (d^2 bit domain)
    #pragma unroll
    for (int a = 0; a < 2; ++a)
        #pragma unroll
        for (int r = 0; r < 4; ++r) {
            float p = rowP[a][r], n = rowN[a][r];
            #pragma unroll
            for (int off = 1; off < 16; off <<= 1) {
                p = fmaxf(p, __shfl_xor(p, off));
                n = fminf(n, __shfl_xor(n, off));
            }
            rowP[a][r] = p; rowN[a][r] = n;
        }
    if (lr == 0) {
        #pragma unroll
        for (int a = 0; a < 2; ++a)
            #pragma unroll
            for (int r = 0; r < 4; ++r) {
                int row = i0 + wave * 32 + a * 16 + quad * 4 + r;
                float pd2 = fmaxf(sqi4[a][r] + rowP[a][r], 0.f);   // -inf -> 0 (empty pos)
                float nd2 = fmaxf(sqi4[a][r] + rowN[a][r], 0.f);   // +inf stays +inf (empty neg)
                atomicMax(&ap[row], __float_as_uint(pd2));
                atomicMin(&an[row], __float_as_uint(nd2));
            }
    }
}

// ---------- loss: single block, reads d^2, sqrt here, writes out[0] ----------
__global__ __launch_bounds__(256) void loss_kernel(const float* __restrict__ ap,
                                                   const float* __restrict__ an,
                                                   float* __restrict__ out) {
    int tid = threadIdx.x;
    float sum = 0.f;
    #pragma unroll
    for (int k = 0; k < 8; ++k) {
        int i = k * 1024 + tid * 4;
        f32x4 a4 = *(const f32x4*)&ap[i];
        f32x4 n4 = *(const f32x4*)&an[i];
        #pragma unroll
        for (int c = 0; c < 4; ++c) {
            float apd = __builtin_amdgcn_sqrtf(a4[c]);
            float anv = n4[c];
            float and_ = (anv < INFINITY) ? __builtin_amdgcn_sqrtf(anv) : NEG_FILL;
            sum += fmaxf(0.f, MARGIN_V - (and_ - apd));
        }
    }
    #pragma unroll
    for (int off = 32; off >= 1; off >>= 1) sum += __shfl_xor(sum, off);
    __shared__ float s4[4];
    if ((tid & 63) == 0) s4[tid >> 6] = sum;
    __syncthreads();
    if (tid == 0) out[0] = (s4[0] + s4[1] + s4[2] + s4[3]) * (1.0f / (float)N);
}

extern "C" void kernel_launch(void* const* d_in, const int* in_sizes, int n_in,
                              void* d_out, int out_size, void* d_ws, size_t ws_size,
                              hipStream_t stream) {
    const float* F   = (const float*)d_in[0];
    const int*   lab = (const int*)d_in[1];

    unsigned short* Fb = (unsigned short*)d_ws;          // 2 MB
    float*          sq = (float*)(Fb + (size_t)N * D);   // 32 KB
    unsigned*       ap = (unsigned*)(sq + N);            // 32 KB
    unsigned*       an = ap + N;                         // 32 KB

    convert_kernel<<<N / 4, 256, 0, stream>>>(F, Fb, sq, ap, an);
    gemm_kernel<<<512, 256, 0, stream>>>(Fb, sq, lab, ap, an);
    loss_kernel<<<1, 256, 0, stream>>>((const float*)ap, (const float*)an, (float*)d_out);
}

// Round 6
// 86.561 us; speedup vs baseline: 4.5243x; 1.0005x over previous
//
#include <hip/hip_runtime.h>
#include <hip/hip_bf16.h>
#include <math.h>

#define N 8192
#define D 128
#define MARGIN_V 0.3f
#define NEG_FILL 1000000.0f

typedef short bf16x8 __attribute__((ext_vector_type(8)));
typedef float f32x4  __attribute__((ext_vector_type(4)));

__device__ __forceinline__ void g2l16(const void* g, void* l) {
    __builtin_amdgcn_global_load_lds(
        (const __attribute__((address_space(1))) void*)g,
        (__attribute__((address_space(3))) void*)l, 16, 0, 0);
}

// ---------- convert: F fp32 -> bf16, sq[i] = ||f_i||^2; init ap/an ----------
__global__ __launch_bounds__(256) void convert_kernel(const float* __restrict__ F,
                                                      unsigned short* __restrict__ Fb,
                                                      float* __restrict__ sq,
                                                      unsigned* __restrict__ ap,
                                                      unsigned* __restrict__ an) {
    int row  = blockIdx.x * 4 + (threadIdx.x >> 6);
    int lane = threadIdx.x & 63;
    float2 v = *(const float2*)&F[row * D + lane * 2];
    float s = v.x * v.x + v.y * v.y;
    __hip_bfloat162 t = __float22bfloat162_rn(v);
    *(unsigned int*)&Fb[row * D + lane * 2] = *(unsigned int*)&t;
    #pragma unroll
    for (int off = 32; off >= 1; off >>= 1) s += __shfl_xor(s, off);
    if (lane == 0) sq[row] = s;
    int gid = blockIdx.x * 256 + threadIdx.x;
    if (gid < N) { ap[gid] = 0u; an[gid] = 0x7F800000u; }   // 0.0f / +inf (d^2 domain)
}

// ---------- gemm: 128-row strip x 1024-col chunk per block ----------
// grid 512 = 64 strips x 8 chunks = 2 blocks/CU. A resident in regs,
// B double-buffered (16 tiles of 64 cols). Wave split 2x2: each wave
// computes 64 rows x 32 cols -> B LDS reads halve vs 32x64 split.
// Mining in u = sqj - 2c domain, register-accumulated; sqrt deferred.
// LDS chunk swizzle: 16B chunk kc of row r stored at pos (kc&8)|((kc^r)&7).
__global__ __launch_bounds__(256, 2) void gemm_kernel(const unsigned short* __restrict__ Fb,
                                                      const float* __restrict__ sq,
                                                      const int* __restrict__ lab,
                                                      unsigned* __restrict__ ap,
                                                      unsigned* __restrict__ an) {
    __shared__ __align__(16) unsigned short As[128 * 128];    // 32 KB
    __shared__ __align__(16) unsigned short Bs[2][64 * 128];  // 2 x 16 KB
    __shared__ float sqj_s[1024];
    __shared__ int   labj_s[1024];
    __shared__ float sqi_s[128];
    __shared__ int   labi_s[128];

    const int bi = blockIdx.x & 63;
    const int jc = blockIdx.x >> 6;
    const int i0 = bi * 128;
    const int jbase0 = jc * 1024;
    const int tid  = threadIdx.x;
    const int wave = tid >> 6, lane = tid & 63;
    const int wy = wave >> 1, wx = wave & 1;   // wave = 64 rows (wy) x 32 cols (wx)
    const int quad = lane >> 4, lr = lane & 15;

    // stage sq/lab for this block's rows and cols
    {
        f32x4 v = *(const f32x4*)&sq[jbase0 + tid * 4];
        *(f32x4*)&sqj_s[tid * 4] = v;
        int4 w4 = *(const int4*)&lab[jbase0 + tid * 4];
        *(int4*)&labj_s[tid * 4] = w4;
    }
    if (tid < 128) { sqi_s[tid] = sq[i0 + tid]; labi_s[tid] = lab[i0 + tid]; }

    // stage A tile (128 rows x 128 k), swizzled
    #pragma unroll
    for (int it = 0; it < 8; ++it) {
        int c_id = it * 256 + tid;
        int row = c_id >> 4, p = c_id & 15;
        int sc = (p & 8) | ((p ^ row) & 7);
        g2l16(Fb + (size_t)(i0 + row) * D + sc * 8, (char*)As + c_id * 16);
    }
    // stage B tile 0
    #pragma unroll
    for (int it = 0; it < 4; ++it) {
        int c_id = it * 256 + tid;
        int row = c_id >> 4, p = c_id & 15;
        int sc = (p & 8) | ((p ^ row) & 7);
        g2l16(Fb + (size_t)(jbase0 + row) * D + sc * 8, (char*)&Bs[0][0] + c_id * 16);
    }
    __syncthreads();

    // cache A fragments in registers for the whole block: 4 row-frags x 4 ks
    bf16x8 af[4][4];
    #pragma unroll
    for (int a = 0; a < 4; ++a)
        #pragma unroll
        for (int ks = 0; ks < 4; ++ks) {
            int row = wy * 64 + a * 16 + lr;
            int kc  = ks * 4 + quad;
            int pos = (kc & 8) | ((kc ^ row) & 7);
            af[a][ks] = *(const bf16x8*)&As[row * 128 + pos * 8];
        }
    f32x4 sqi4[4]; int4 labi4[4];
    #pragma unroll
    for (int a = 0; a < 4; ++a) {
        int base = wy * 64 + a * 16 + quad * 4;
        sqi4[a]  = *(const f32x4*)&sqi_s[base];
        labi4[a] = *(const int4*)&labi_s[base];
    }

    float rowP[4][4], rowN[4][4];
    #pragma unroll
    for (int a = 0; a < 4; ++a)
        #pragma unroll
        for (int r = 0; r < 4; ++r) { rowP[a][r] = -INFINITY; rowN[a][r] = INFINITY; }

    #pragma unroll 2
    for (int t = 0; t < 16; ++t) {
        // prefetch next B tile into the other buffer
        if (t < 15) {
            #pragma unroll
            for (int it = 0; it < 4; ++it) {
                int c_id = it * 256 + tid;
                int row = c_id >> 4, p = c_id & 15;
                int sc = (p & 8) | ((p ^ row) & 7);
                g2l16(Fb + (size_t)(jbase0 + (t + 1) * 64 + row) * D + sc * 8,
                      (char*)&Bs[(t + 1) & 1][0] + c_id * 16);
            }
        }
        // per-tile column metadata (this wave's 32 cols)
        float sqj_l[2]; int labj_l[2];
        #pragma unroll
        for (int b = 0; b < 2; ++b) {
            int cl = t * 64 + wx * 32 + b * 16 + lr;
            sqj_l[b]  = sqj_s[cl];
            labj_l[b] = labj_s[cl];
        }
        // MFMA on current buffer: 4a x 2b x 4ks = 32 MFMAs
        f32x4 acc[4][2];
        #pragma unroll
        for (int a = 0; a < 4; ++a)
            #pragma unroll
            for (int b = 0; b < 2; ++b) acc[a][b] = {0.f, 0.f, 0.f, 0.f};
        #pragma unroll
        for (int ks = 0; ks < 4; ++ks) {
            bf16x8 bfr[2];
            #pragma unroll
            for (int b = 0; b < 2; ++b) {
                int rb  = wx * 32 + b * 16 + lr;
                int kc  = ks * 4 + quad;
                int pos = (kc & 8) | ((kc ^ rb) & 7);
                bfr[b] = *(const bf16x8*)&Bs[t & 1][rb * 128 + pos * 8];
            }
            #pragma unroll
            for (int a = 0; a < 4; ++a)
                #pragma unroll
                for (int b = 0; b < 2; ++b)
                    acc[a][b] = __builtin_amdgcn_mfma_f32_16x16x32_bf16(af[a][ks], bfr[b], acc[a][b], 0, 0, 0);
        }
        __syncthreads();   // Bs reads done; prefetch drained; safe to overwrite next iter

        // epilogue: u = sqj - 2c mining, register-resident
        #pragma unroll
        for (int a = 0; a < 4; ++a)
            #pragma unroll
            for (int b = 0; b < 2; ++b)
                #pragma unroll
                for (int r = 0; r < 4; ++r) {
                    float u = fmaf(acc[a][b][r], -2.0f, sqj_l[b]);
                    bool same = (labi4[a][r] == labj_l[b]);
                    rowP[a][r] = fmaxf(rowP[a][r], same ? u : -INFINITY);
                    rowN[a][r] = fminf(rowN[a][r], same ? INFINITY : u);
                }
    }

    // reduce over the 16 lr lanes, then atomically combine (d^2 bit domain);
    // the two wx waves of each row-half merge via the same atomics.
    #pragma unroll
    for (int a = 0; a < 4; ++a)
        #pragma unroll
        for (int r = 0; r < 4; ++r) {
            float p = rowP[a][r], n = rowN[a][r];
            #pragma unroll
            for (int off = 1; off < 16; off <<= 1) {
                p = fmaxf(p, __shfl_xor(p, off));
                n = fminf(n, __shfl_xor(n, off));
            }
            rowP[a][r] = p; rowN[a][r] = n;
        }
    if (lr == 0) {
        #pragma unroll
        for (int a = 0; a < 4; ++a)
            #pragma unroll
            for (int r = 0; r < 4; ++r) {
                int row = i0 + wy * 64 + a * 16 + quad * 4 + r;
                float pd2 = fmaxf(sqi4[a][r] + rowP[a][r], 0.f);   // -inf -> 0 (empty pos)
                float nd2 = fmaxf(sqi4[a][r] + rowN[a][r], 0.f);   // +inf stays +inf (empty neg)
                atomicMax(&ap[row], __float_as_uint(pd2));
                atomicMin(&an[row], __float_as_uint(nd2));
            }
    }
}

// ---------- loss: single block, reads d^2, sqrt here, writes out[0] ----------
__global__ __launch_bounds__(256) void loss_kernel(const float* __restrict__ ap,
                                                   const float* __restrict__ an,
                                                   float* __restrict__ out) {
    int tid = threadIdx.x;
    float sum = 0.f;
    #pragma unroll
    for (int k = 0; k < 8; ++k) {
        int i = k * 1024 + tid * 4;
        f32x4 a4 = *(const f32x4*)&ap[i];
        f32x4 n4 = *(const f32x4*)&an[i];
        #pragma unroll
        for (int c = 0; c < 4; ++c) {
            float apd = __builtin_amdgcn_sqrtf(a4[c]);
            float anv = n4[c];
            float and_ = (anv < INFINITY) ? __builtin_amdgcn_sqrtf(anv) : NEG_FILL;
            sum += fmaxf(0.f, MARGIN_V - (and_ - apd));
        }
    }
    #pragma unroll
    for (int off = 32; off >= 1; off >>= 1) sum += __shfl_xor(sum, off);
    __shared__ float s4[4];
    if ((tid & 63) == 0) s4[tid >> 6] = sum;
    __syncthreads();
    if (tid == 0) out[0] = (s4[0] + s4[1] + s4[2] + s4[3]) * (1.0f / (float)N);
}

extern "C" void kernel_launch(void* const* d_in, const int* in_sizes, int n_in,
                              void* d_out, int out_size, void* d_ws, size_t ws_size,
                              hipStream_t stream) {
    const float* F   = (const float*)d_in[0];
    const int*   lab = (const int*)d_in[1];

    unsigned short* Fb = (unsigned short*)d_ws;          // 2 MB
    float*          sq = (float*)(Fb + (size_t)N * D);   // 32 KB
    unsigned*       ap = (unsigned*)(sq + N);            // 32 KB
    unsigned*       an = ap + N;                         // 32 KB

    convert_kernel<<<N / 4, 256, 0, stream>>>(F, Fb, sq, ap, an);
    gemm_kernel<<<512, 256, 0, stream>>>(Fb, sq, lab, ap, an);
    loss_kernel<<<1, 256, 0, stream>>>((const float*)ap, (const float*)an, (float*)d_out);
}